// Round 1
// baseline (1910.327 us; speedup 1.0000x reference)
//
#include <hip/hip_runtime.h>
#include <cstdint>
#include <cstddef>

// ---------------- types & helpers ----------------
typedef unsigned short u16;
typedef __bf16 bf16x8 __attribute__((ext_vector_type(8)));
typedef u16    u16x8  __attribute__((ext_vector_type(8)));
typedef float  f32x4  __attribute__((ext_vector_type(4)));

static __device__ __forceinline__ u16 f2bf(float f) {
  uint32_t u = __builtin_bit_cast(uint32_t, f);
  u += 0x7FFFu + ((u >> 16) & 1u);           // round-to-nearest-even
  return (u16)(u >> 16);
}
static __device__ __forceinline__ float bf2f(u16 h) {
  return __builtin_bit_cast(float, (uint32_t)h << 16);
}
static __device__ __forceinline__ bf16x8 as_bf(u16x8 v) {
  union { u16x8 u; bf16x8 b; } x; x.u = v; return x.b;
}

#define GLD_LDS(src, dst)                                                      \
  __builtin_amdgcn_global_load_lds(                                            \
      (const __attribute__((address_space(1))) void*)(const void*)(src),       \
      (__attribute__((address_space(3))) void*)(void*)(dst), 16, 0, 0)

// problem constants
#define T_TOK 16384
#define DDIM  1024
#define EEXP  8
#define HDIM  4096
#define BM    128
#define MAXTILES 264         // sum ceil(c_e/128) <= 263
#define MAXSLOTS 33792       // 32768 + 8*127 padded, rounded up

// ---------------- transpose + fp32->bf16 cast ----------------
// in: per-expert R x C (row-major), out: per-expert C x R (row-major, bf16)
__global__ __launch_bounds__(256) void transpose_cast(
    const float* __restrict__ in, u16* __restrict__ out, int R, int C) {
  __shared__ float t[32][33];
  int e = blockIdx.z;
  const float* src = in + (size_t)e * R * C;
  u16* dst = out + (size_t)e * R * C;
  int c0 = blockIdx.x * 32, r0 = blockIdx.y * 32;
  int tx = threadIdx.x & 31, ty = threadIdx.x >> 5;   // 32 x 8
#pragma unroll
  for (int i = 0; i < 4; i++)
    t[ty + i * 8][tx] = src[(size_t)(r0 + ty + i * 8) * C + c0 + tx];
  __syncthreads();
#pragma unroll
  for (int i = 0; i < 4; i++)
    dst[(size_t)(c0 + ty + i * 8) * R + r0 + tx] = f2bf(t[tx][ty + i * 8]);
}

// ---------------- router: fp32 logits, top-2, softmax; fused x->bf16 -------
__global__ __launch_bounds__(256) void router_kernel(
    const float* __restrict__ x, const float* __restrict__ Wg,
    const float* __restrict__ bg, u16* __restrict__ xbf,
    int2* __restrict__ tok_e, float2* __restrict__ tok_g,
    int* __restrict__ counts) {
  int w = threadIdx.x >> 6, lane = threadIdx.x & 63;
  int t = blockIdx.x * 4 + w;
  const float* xr = x + (size_t)t * DDIM;
  float acc[EEXP] = {0.f, 0.f, 0.f, 0.f, 0.f, 0.f, 0.f, 0.f};
#pragma unroll
  for (int j = 0; j < DDIM / 64; j++) {
    int d = j * 64 + lane;
    float xv = xr[d];
    xbf[(size_t)t * DDIM + d] = f2bf(xv);
    const float4* wv = (const float4*)(Wg + (size_t)d * EEXP);
    float4 wa = wv[0], wb = wv[1];
    acc[0] += xv * wa.x; acc[1] += xv * wa.y;
    acc[2] += xv * wa.z; acc[3] += xv * wa.w;
    acc[4] += xv * wb.x; acc[5] += xv * wb.y;
    acc[6] += xv * wb.z; acc[7] += xv * wb.w;
  }
#pragma unroll
  for (int e = 0; e < EEXP; e++) {
    float v = acc[e];
    for (int s = 32; s; s >>= 1) v += __shfl_xor(v, s);
    acc[e] = v + bg[e];
  }
  // top-2 (lowest index wins ties, matching lax.top_k)
  int e0 = 0; float v0 = acc[0];
#pragma unroll
  for (int e = 1; e < EEXP; e++) if (acc[e] > v0) { v0 = acc[e]; e0 = e; }
  int e1 = -1; float v1 = -3.402823466e38f;
#pragma unroll
  for (int e = 0; e < EEXP; e++)
    if (e != e0 && acc[e] > v1) { v1 = acc[e]; e1 = e; }
  float p0 = 1.f / (1.f + expf(v1 - v0));
  float p1 = 1.f - p0;
  if (lane == 0) {
    atomicAdd(&counts[e0], 1);
    atomicAdd(&counts[e1], 1);
    tok_e[t] = make_int2(e0, e1);
    tok_g[t] = make_float2(p0, p1);
  }
}

// ---------------- scan: per-expert bases (BM-padded) + tile table ----------
__global__ void scan_kernel(const int* __restrict__ counts,
                            int* __restrict__ expBase,
                            int* __restrict__ tileExpert,
                            int* __restrict__ tileRow0,
                            int* __restrict__ nTiles) {
  if (threadIdx.x != 0 || blockIdx.x != 0) return;
  int base = 0, nt = 0;
  for (int e = 0; e < EEXP; e++) {
    expBase[e] = base;
    int c = counts[e];
    int tiles = (c + BM - 1) >> 7;
    for (int i = 0; i < tiles; i++) {
      tileExpert[nt] = e;
      tileRow0[nt] = base + i * BM;
      nt++;
    }
    base += tiles << 7;
  }
  *nTiles = nt;
}

// ---------------- scatter: slot assignment -------------------------------
__global__ __launch_bounds__(256) void scatter_kernel(
    const int2* __restrict__ tok_e, int* __restrict__ cursor,
    const int* __restrict__ expBase, int* __restrict__ rowmap,
    int2* __restrict__ tokslot) {
  int t = blockIdx.x * 256 + threadIdx.x;
  int2 e = tok_e[t];
  int s0 = expBase[e.x] + atomicAdd(&cursor[e.x], 1);
  int s1 = expBase[e.y] + atomicAdd(&cursor[e.y], 1);
  rowmap[s0] = t;
  rowmap[s1] = t;
  tokslot[t] = make_int2(s0, s1);
}

// ---------------- grouped GEMM: C[slot][n] = act(A[row(slot)] . Bt[e][n] + bias[e][n])
// m97-style: 128x128 tile, BK=64, 4 waves, mfma 16x16x32 bf16,
// global_load_lds width-16 staging, per-lane-gathered A source.
template <bool RELU, bool GATHER>
__global__ __launch_bounds__(256) void moe_gemm(
    const u16* __restrict__ A,      // [rows][K] bf16
    const u16* __restrict__ Bt,     // [E][N][K] bf16
    const float* __restrict__ bias, // [E][N]
    u16* __restrict__ C,            // [slots][N] bf16
    const int* __restrict__ rowmap, // slot -> token (GATHER)
    const int* __restrict__ tileExpert, const int* __restrict__ tileRow0,
    const int* __restrict__ nTiles, int N, int K) {
  __shared__ __align__(16) u16 As[BM * 64];
  __shared__ __align__(16) u16 Bs[BM * 64];
  int nt = N >> 7;
  int mtile = (int)blockIdx.x / nt;
  if (mtile >= *nTiles) return;
  int ntile = (int)blockIdx.x % nt;
  int e = tileExpert[mtile];
  int row0 = tileRow0[mtile];
  const u16* Bm = Bt + (size_t)e * N * K;
  const float* bb = bias + (size_t)e * N;
  int ncol0 = ntile << 7;

  int tid = threadIdx.x, lane = tid & 63, w = tid >> 6;
  int wr = w >> 1, wc = w & 1;

  // staging source pointers: chunk cc covers LDS elems [cc*8, cc*8+8)
  // of a [128 rows][64 k] tile; row = cc>>3, kchunk = cc&7.
  const u16* asrc[4];
  const u16* bsrc[4];
#pragma unroll
  for (int j = 0; j < 4; j++) {
    int cc = (w * 4 + j) * 64 + lane;
    int row = cc >> 3, kc = cc & 7;
    int slot = row0 + row;
    int ar = GATHER ? rowmap[slot] : slot;
    asrc[j] = A + (size_t)ar * K + kc * 8;
    bsrc[j] = Bm + (size_t)(ncol0 + row) * K + kc * 8;
  }

  f32x4 acc[4][4] = {};

  for (int k0 = 0; k0 < K; k0 += 64) {
    __syncthreads();  // previous compute done before overwriting LDS
#pragma unroll
    for (int j = 0; j < 4; j++)
      GLD_LDS(asrc[j] + k0, &As[(w * 4 + j) * 512]);
#pragma unroll
    for (int j = 0; j < 4; j++)
      GLD_LDS(bsrc[j] + k0, &Bs[(w * 4 + j) * 512]);
    __syncthreads();  // staging complete (compiler drains vmcnt before barrier)
#pragma unroll
    for (int kk = 0; kk < 64; kk += 32) {
      u16x8 av[4], bv[4];
#pragma unroll
      for (int m = 0; m < 4; m++)
        av[m] = *reinterpret_cast<const u16x8*>(
            &As[(wr * 64 + m * 16 + (lane & 15)) * 64 + kk + (lane >> 4) * 8]);
#pragma unroll
      for (int n = 0; n < 4; n++)
        bv[n] = *reinterpret_cast<const u16x8*>(
            &Bs[(wc * 64 + n * 16 + (lane & 15)) * 64 + kk + (lane >> 4) * 8]);
#pragma unroll
      for (int m = 0; m < 4; m++)
#pragma unroll
        for (int n = 0; n < 4; n++)
          acc[m][n] = __builtin_amdgcn_mfma_f32_16x16x32_bf16(
              as_bf(av[m]), as_bf(bv[n]), acc[m][n], 0, 0, 0);
    }
  }

  // epilogue: C/D map col=lane&15, row=(lane>>4)*4+reg
  int r4 = (lane >> 4) * 4;
  int cl = lane & 15;
#pragma unroll
  for (int m = 0; m < 4; m++) {
    int rbase = row0 + wr * 64 + m * 16 + r4;
#pragma unroll
    for (int n = 0; n < 4; n++) {
      int col = ncol0 + wc * 64 + n * 16 + cl;
      float bval = bb[col];
#pragma unroll
      for (int j = 0; j < 4; j++) {
        float v = acc[m][n][j] + bval;
        if (RELU) v = fmaxf(v, 0.f);
        C[(size_t)(rbase + j) * N + col] = f2bf(v);
      }
    }
  }
}

// ---------------- combine: out[t] = g0*Y[s0] + g1*Y[s1] --------------------
__global__ __launch_bounds__(256) void combine_kernel(
    const u16* __restrict__ Y, const int2* __restrict__ tokslot,
    const float2* __restrict__ tok_g, float* __restrict__ out) {
  int gid = blockIdx.x * 256 + threadIdx.x;  // T * 128 threads, 8 elems each
  int t = gid >> 7, seg = (gid & 127) * 8;
  int2 s = tokslot[t];
  float2 g = tok_g[t];
  u16x8 y0 = *reinterpret_cast<const u16x8*>(Y + (size_t)s.x * DDIM + seg);
  u16x8 y1 = *reinterpret_cast<const u16x8*>(Y + (size_t)s.y * DDIM + seg);
  float* op = out + (size_t)t * DDIM + seg;
#pragma unroll
  for (int i = 0; i < 8; i++)
    op[i] = g.x * bf2f(y0[i]) + g.y * bf2f(y1[i]);
}

// ---------------- launch ----------------
extern "C" void kernel_launch(void* const* d_in, const int* in_sizes, int n_in,
                              void* d_out, int out_size, void* d_ws,
                              size_t ws_size, hipStream_t stream) {
  (void)in_sizes; (void)n_in; (void)out_size; (void)ws_size;
  const float* x  = (const float*)d_in[0];
  const float* Wg = (const float*)d_in[1];
  const float* bg = (const float*)d_in[2];
  const float* W1 = (const float*)d_in[3];
  const float* b1 = (const float*)d_in[4];
  const float* W2 = (const float*)d_in[5];
  const float* b2 = (const float*)d_in[6];
  float* out = (float*)d_out;

  char* ws = (char*)d_ws;
  size_t o = 0;
  u16* W1T = (u16*)(ws + o); o += (size_t)EEXP * DDIM * HDIM * 2;   // 67,108,864
  u16* W2T = (u16*)(ws + o); o += (size_t)EEXP * HDIM * DDIM * 2;   // 67,108,864
  u16* xbf = (u16*)(ws + o); o += (size_t)T_TOK * DDIM * 2;         // 33,554,432
  u16* Hbuf = (u16*)(ws + o); o += (size_t)MAXSLOTS * HDIM * 2;     // 276,824,064
  u16* Ybuf = (u16*)(ws + o); o += (size_t)MAXSLOTS * DDIM * 2;     // 69,206,016
  int* rowmap = (int*)(ws + o); o += (size_t)MAXSLOTS * 4;
  int2* tok_e = (int2*)(ws + o); o += (size_t)T_TOK * 8;
  float2* tok_g = (float2*)(ws + o); o += (size_t)T_TOK * 8;
  int2* tokslot = (int2*)(ws + o); o += (size_t)T_TOK * 8;
  int* counts = (int*)(ws + o); o += 8 * 4;
  int* cursor = (int*)(ws + o); o += 8 * 4;
  int* expBase = (int*)(ws + o); o += 8 * 4;
  int* nTiles = (int*)(ws + o); o += 8 * 4;
  int* tileExpert = (int*)(ws + o); o += MAXTILES * 4;
  int* tileRow0 = (int*)(ws + o); o += MAXTILES * 4;

  // zero counts+cursor (contiguous) and rowmap (pad slots -> token 0)
  hipMemsetAsync(counts, 0, 16 * 4, stream);
  hipMemsetAsync(rowmap, 0, (size_t)MAXSLOTS * 4, stream);

  // weight transpose+cast: W1 (E,D,H) -> W1T (E,H,D); W2 (E,H,D) -> W2T (E,D,H)
  transpose_cast<<<dim3(HDIM / 32, DDIM / 32, EEXP), 256, 0, stream>>>(W1, W1T, DDIM, HDIM);
  transpose_cast<<<dim3(DDIM / 32, HDIM / 32, EEXP), 256, 0, stream>>>(W2, W2T, HDIM, DDIM);

  router_kernel<<<T_TOK / 4, 256, 0, stream>>>(x, Wg, bg, xbf, tok_e, tok_g, counts);
  scan_kernel<<<1, 64, 0, stream>>>(counts, expBase, tileExpert, tileRow0, nTiles);
  scatter_kernel<<<T_TOK / 256, 256, 0, stream>>>(tok_e, cursor, expBase, rowmap, tokslot);

  // GEMM1: H = relu(x[rowmap] @ W1[e] + b1[e])   (N=4096, K=1024)
  moe_gemm<true, true><<<MAXTILES * (HDIM / 128), 256, 0, stream>>>(
      xbf, W1T, b1, Hbuf, rowmap, tileExpert, tileRow0, nTiles, HDIM, DDIM);
  // GEMM2: Y = H @ W2[e] + b2[e]                 (N=1024, K=4096)
  moe_gemm<false, false><<<MAXTILES * (DDIM / 128), 256, 0, stream>>>(
      Hbuf, W2T, b2, Ybuf, nullptr, tileExpert, tileRow0, nTiles, DDIM, HDIM);

  combine_kernel<<<(T_TOK * (DDIM / 8)) / 256, 256, 0, stream>>>(Ybuf, tokslot, tok_g, out);
}